// Round 7
// baseline (162.137 us; speedup 1.0000x reference)
//
#include <hip/hip_runtime.h>
#include <cstddef>

namespace {

constexpr int B = 4, V = 20000, P = 400000, NN = 50000, MP = 32;
constexpr float GAMMA = 10.0f, INV_GAMMA = 0.1f;
constexpr float KSOFT = 2.0f;
constexpr float THRESH = 1.0f;
constexpr float W_WL = 1.0f, W_CONG = 0.5f;
constexpr int BPB = 128;                   // phase-B blocks per batch (512 blocks = 2/CU)
constexpr int NET_GRID = BPB * B;          // 512 blocks, 4 waves
constexpr int GRPS = 7;                    // 112 contiguous nets per wave-stream
constexpr int NPW = GRPS * 16;             // 112
constexpr int A_SUBS = 196;                // phase A: 196*256 = 50176 >= NN
constexpr int A_GRID = A_SUBS * B;
constexpr int PREP_N = NN * MP;            // 1.6M, largest fused-front range
constexpr int TCH = 32;                    // tail: 2-row chunks per batch (128 blocks)

typedef __attribute__((ext_vector_type(8)))  short bf16x8;
typedef __attribute__((ext_vector_type(16))) float f32x16;

__device__ __forceinline__ float fast_rcp(float x) { return __builtin_amdgcn_rcpf(x); }
__device__ __forceinline__ short f2bf(float f) {
    unsigned u = __float_as_uint(f);
    u += 0x7fffu + ((u >> 16) & 1u);
    return (short)(u >> 16);
}
template <int CTRL>
__device__ __forceinline__ float dpp_mov(float x, float id) {
    return __int_as_float(__builtin_amdgcn_update_dpp(
        __float_as_int(id), __float_as_int(x), CTRL, 0xf, 0xf, false));
}
__device__ __forceinline__ float rdlane(float x, int l) {
    return __int_as_float(__builtin_amdgcn_readlane(__float_as_int(x), l));
}
#define DPP5(x, OP, ID)                              \
    x = OP(x, dpp_mov<0x111>(x, ID));                \
    x = OP(x, dpp_mov<0x112>(x, ID));                \
    x = OP(x, dpp_mov<0x114>(x, ID));                \
    x = OP(x, dpp_mov<0x118>(x, ID));                \
    x = OP(x, dpp_mov<0x142>(x, ID));
__device__ __forceinline__ float op_add(float a, float b) { return a + b; }

// Fused front: zero accumulators/ticket + pin_pos (macro data gathered inline,
// mac[] eliminated) + n2p transpose — ONE launch (they are independent).
__global__ void __launch_bounds__(256)
front_kernel(const float* __restrict__ positions,
             const float* __restrict__ rot_onehot,
             const int* __restrict__ pin_to_macro,
             const float* __restrict__ pin_offsets,
             const int* __restrict__ n2p,
             int* __restrict__ n2pT,
             float* __restrict__ pin_pos,
             float* __restrict__ zacc,      // hpwl[B] + pen[B]
             int* __restrict__ cnt) {       // tail ticket counters [B]
    int i = blockIdx.x * blockDim.x + threadIdx.x;
    if (i < 2 * B) zacc[i] = 0.0f;
    if (i < B) cnt[i] = 0;
    if (i < B * P / 2) {
        int b = i / (P / 2);
        int t = i - b * (P / 2);               // pin-pair index
        int2 m2 = ((const int2*)pin_to_macro)[t];
        float4 o2 = ((const float4*)pin_offsets)[t];
        const float2* pos2 = (const float2*)positions + (size_t)b * V;
        const float4* rot4 = (const float4*)rot_onehot + (size_t)b * V;
        float2 p0 = pos2[m2.x], p1 = pos2[m2.y];
        float4 w0 = rot4[m2.x], w1 = rot4[m2.y];
        float c0 = w0.x - w0.z, s0 = w0.y - w0.w;
        float c1 = w1.x - w1.z, s1 = w1.y - w1.w;
        float4 r;
        r.x = p0.x + c0 * o2.x - s0 * o2.y;
        r.y = p0.y + s0 * o2.x + c0 * o2.y;
        r.z = p1.x + c1 * o2.z - s1 * o2.w;
        r.w = p1.y + s1 * o2.z + c1 * o2.w;
        ((float4*)pin_pos)[i] = r;             // [b][2t..2t+1] as before
    }
    if (i < PREP_N) {
        int n = i >> 5, j = i & 31;
        n2pT[j * NN + n] = n2p[i];
    }
}

// Phase A (byte-identical to R6): one net per LANE; full gather preload; also
// emits the per-net factor record for rudy (4 exp per NET, hidden under the
// gather latency).
__global__ void __launch_bounds__(256)
bbox_kernel(const float* __restrict__ pin_pos,
            const int* __restrict__ n2pT,
            const float* __restrict__ net_weights,
            float4* __restrict__ fac,      // B*NN*2 float4 records
            float* __restrict__ hpwl) {
    __shared__ float hps[4];
    int blk = blockIdx.x;
    int xcd = blk & 7;
    int b = xcd >> 1;
    int sub = ((blk >> 3) << 1) | (xcd & 1);
    int tid = threadIdx.x;
    int wave = tid >> 6;
    int lane = tid & 63;

    int n = sub * 256 + wave * 64 + lane;
    bool inrange = n < NN;
    int nc = inrange ? n : (NN - 1);

    const float2* pp = (const float2*)(pin_pos + (size_t)b * P * 2);

    int pi[MP];
    #pragma unroll
    for (int j = 0; j < MP; ++j) pi[j] = n2pT[j * NN + nc];

    float2 q[MP];
    #pragma unroll
    for (int j = 0; j < MP; ++j) q[j] = pp[pi[j] >= 0 ? pi[j] : 0];

    float ex1 = 0.f, ex2 = 0.f, ey1 = 0.f, ey2 = 0.f;
    float vxmax = -1e30f, vxmin = 1e30f, vymax = -1e30f, vymin = 1e30f;
    #pragma unroll
    for (int j = 0; j < MP; ++j) {
        bool v = pi[j] >= 0;
        float e1x = __expf(GAMMA * q[j].x);
        float e1y = __expf(GAMMA * q[j].y);
        ex1 += v ? e1x : 0.f;
        ex2 += v ? fast_rcp(e1x) : 0.f;
        ey1 += v ? e1y : 0.f;
        ey2 += v ? fast_rcp(e1y) : 0.f;
        vxmax = fmaxf(vxmax, v ? q[j].x : -1e30f);
        vxmin = fminf(vxmin, v ? q[j].x :  1e30f);
        vymax = fmaxf(vymax, v ? q[j].y : -1e30f);
        vymin = fminf(vymin, v ? q[j].y :  1e30f);
    }
    float w = net_weights[nc];
    float wl = __logf(ex1 * ex2 * ey1 * ey2) * INV_GAMMA;
    float hp = inrange ? wl * w : 0.f;

    if (inrange) {
        float xmin = (vxmin + 1.0f) * 31.5f;
        float xmax = (vxmax + 1.0f) * 31.5f;
        float ymin = (vymin + 1.0f) * 31.5f;
        float ymax = (vymax + 1.0f) * 31.5f;
        float sz = fmaxf((xmax - xmin + 1.0f) * (ymax - ymin + 1.0f), 1.0f);
        float ux = __expf(fmaf( KSOFT, xmin, -32.5f * KSOFT));
        float wx = __expf(fmaf(-KSOFT, xmax,  31.5f * KSOFT));
        float uy = __expf(fmaf( KSOFT, ymin, -32.5f * KSOFT));
        float wy = __expf(fmaf(-KSOFT, ymax,  31.5f * KSOFT));
        float cx = fmaf(ux, wx, 1.0f);
        float cy = fmaf(uy, wy, 1.0f) * sz;    // 1/sz folded into A-side
        float4* fp = fac + ((size_t)b * NN + n) * 2;
        fp[0] = make_float4(ux, wx, cx, 0.f);
        fp[1] = make_float4(uy * sz, wy * sz, cy, 0.f);
    }
    DPP5(hp, op_add, 0.0f);
    float tot = rdlane(hp, 31) + rdlane(hp, 63);
    if (lane == 0) hps[wave] = tot;
    __syncthreads();
    if (tid == 0) atomicAdd(&hpwl[b], hps[0] + hps[1] + hps[2] + hps[3]);
}

// Phase B (byte-identical to R6): LDS-stage factor records up front, register
// prefetch one group ahead, exp-free inner loop, private per-wave tile,
// no atomics, one barrier.
__global__ void __launch_bounds__(256)
rudy_kernel(const float4* __restrict__ fac,
            float* __restrict__ slabs) {   // NET_GRID * 4096 (aliases pin_pos)
    __shared__ float lds4[4][4096];            // per-wave tile; head doubles as stage
    int x = blockIdx.x;
    int xcd = x & 7;
    int b = xcd >> 1;
    int sub = ((x >> 3) << 1) | (xcd & 1);     // 0..BPB-1
    int tid = threadIdx.x;
    int wave = tid >> 6;
    int lane = tid & 63;

    int s = sub * 4 + wave;                    // wave-stream id, 0..511
    int s0 = s * NPW;                          // first net of this stream
    const float* ff = (const float*)(fac + (size_t)b * NN * 2);  // dword view

    // ---- stage: 112 nets * 8 dwords = 896 dwords, 14 per lane, coalesced ----
    #pragma unroll
    for (int k = 0; k < 14; ++k) {
        int d = s0 * 8 + k * 64 + lane;        // dword index into batch fac
        lds4[wave][k * 64 + lane] = ff[d < NN * 8 ? d : 0];
    }
    const float4* st = (const float4*)lds4[wave];

    f32x16 acc00, acc01, acc10, acc11;
    #pragma unroll
    for (int r = 0; r < 16; ++r) { acc00[r] = 0.f; acc01[r] = 0.f; acc10[r] = 0.f; acc11[r] = 0.f; }

    int half8 = (lane >> 5) * 8;               // k-slot base for this half-wave
    float g2 = (float)(lane & 31);             // row/col 0..31 (g2+32 via EnH/EpH)

    float En0 = __expf(fmaf(-KSOFT, g2,  32.0f * KSOFT));
    float Ep0 = __expf(fmaf( KSOFT, g2, -32.0f * KSOFT));
    float EnH = __expf(-KSOFT * g2);
    float EpH = __expf( KSOFT * g2);

    if (s0 < NN) {                             // idle tail streams exit fast
        float4 fbc[8], fyc[8];
        #pragma unroll
        for (int j = 0; j < 8; ++j) {
            fbc[j] = st[2 * (half8 + j)];
            fyc[j] = st[2 * (half8 + j) + 1];
        }
        #pragma unroll
        for (int grp = 0; grp < GRPS; ++grp) {
            float4 fbn[8], fyn[8];
            if (grp + 1 < GRPS) {              // prefetch next group's LDS reads
                #pragma unroll
                for (int j = 0; j < 8; ++j) {
                    fbn[j] = st[2 * ((grp + 1) * 16 + half8 + j)];
                    fyn[j] = st[2 * ((grp + 1) * 16 + half8 + j) + 1];
                }
            }
            int nb = s0 + grp * 16 + half8;
            bf16x8 A0, A1, B0, B1;
            #pragma unroll
            for (int j = 0; j < 8; ++j) {
                float4 fb = fbc[j];
                float4 fy = fyc[j];
                float okf = (nb + j < NN) ? 1.0f : 0.0f;
                float b0 = fast_rcp(fmaf(En0, fb.x, fmaf(Ep0, fb.y, fb.z)));
                float b1 = fast_rcp(fmaf(EnH, fb.x, fmaf(EpH, fb.y, fb.z)));
                float a0 = fast_rcp(fmaf(En0, fy.x, fmaf(Ep0, fy.y, fy.z))) * okf;
                float a1 = fast_rcp(fmaf(EnH, fy.x, fmaf(EpH, fy.y, fy.z))) * okf;
                A0[j] = f2bf(a0); A1[j] = f2bf(a1);
                B0[j] = f2bf(b0); B1[j] = f2bf(b1);
            }
            acc00 = __builtin_amdgcn_mfma_f32_32x32x16_bf16(A0, B0, acc00, 0, 0, 0);
            acc01 = __builtin_amdgcn_mfma_f32_32x32x16_bf16(A0, B1, acc01, 0, 0, 0);
            acc10 = __builtin_amdgcn_mfma_f32_32x32x16_bf16(A1, B0, acc10, 0, 0, 0);
            acc11 = __builtin_amdgcn_mfma_f32_32x32x16_bf16(A1, B1, acc11, 0, 0, 0);
            if (grp + 1 < GRPS) {
                #pragma unroll
                for (int j = 0; j < 8; ++j) { fbc[j] = fbn[j]; fyc[j] = fyn[j]; }
            }
        }
    }

    // C/D layout: col=lane&31, row=(r&3)+8*(r>>2)+4*(lane>>5)
    int col = lane & 31, rq = lane >> 5;
    float* wt = lds4[wave];
    #pragma unroll
    for (int r = 0; r < 16; ++r) {
        int row = (r & 3) + 8 * (r >> 2) + 4 * rq;
        wt[row * 64 + col]             = acc00[r];
        wt[row * 64 + col + 32]        = acc01[r];
        wt[(row + 32) * 64 + col]      = acc10[r];
        wt[(row + 32) * 64 + col + 32] = acc11[r];
    }
    __syncthreads();
    float* slab = slabs + ((size_t)b * BPB + sub) * 4096;
    for (int k = tid; k < 4096; k += 256)
        slab[k] = (lds4[0][k] + lds4[1][k]) + (lds4[2][k] + lds4[3][k]);
}

// Fused tail: slab-reduce (with halo recompute, bitwise-identical summation
// order to the old rudy_reduce) + 7x7 conv + penalty + ticket-based finalize.
// 128 blocks = 2 output rows each; XCD-pinned to the slab writers' L2 pair.
__global__ void __launch_bounds__(256)
tail_kernel(const float* __restrict__ slabs,
            const float* __restrict__ hpwl,
            float* __restrict__ pen,
            int* __restrict__ cnt,
            float* __restrict__ out) {
    int blk = blockIdx.x;                       // 128
    int xcd = blk & 7;
    int b = xcd >> 1;
    int sub = ((blk >> 3) << 1) | (xcd & 1);    // 0..TCH-1
    int r0 = sub * 2;                           // first output row
    __shared__ float t2[8][64];                 // rows r0-3 .. r0+4
    int tid = threadIdx.x;

    for (int k = tid; k < 512; k += 256) {
        int r = k >> 6, c = k & 63;
        int row = r0 - 3 + r;
        float v = 0.f;
        if (row >= 0 && row < 64) {
            const float* base = slabs + (size_t)b * BPB * 4096 + row * 64 + c;
            float a0 = 0.f, a1 = 0.f, a2 = 0.f, a3 = 0.f;
            #pragma unroll 4
            for (int s = 0; s < BPB; s += 4) {
                a0 += base[(size_t)(s + 0) * 4096];
                a1 += base[(size_t)(s + 1) * 4096];
                a2 += base[(size_t)(s + 2) * 4096];
                a3 += base[(size_t)(s + 3) * 4096];
            }
            v = (a0 + a1) + (a2 + a3);
        }
        t2[r][c] = v;
    }
    __syncthreads();

    float g1[7];
    #pragma unroll
    for (int i = 0; i < 7; ++i) { float t = (float)(i - 3); g1[i] = __expf(-t * t / 4.5f); }
    float s1 = g1[0] + g1[1] + g1[2] + g1[3] + g1[4] + g1[5] + g1[6];
    float inv = fast_rcp(s1 * s1);

    float p = 0.f;
    if (tid < 128) {                            // 2 rows x 64 cols
        int i = tid >> 6, j = tid & 63;
        float acc = 0.f;
        #pragma unroll
        for (int di = -3; di <= 3; ++di) {
            #pragma unroll
            for (int dj = -3; dj <= 3; ++dj) {
                int jj = j + dj;
                float val = (jj >= 0 && jj < 64) ? t2[i + 3 + di][jj] : 0.f;
                acc += g1[di + 3] * g1[dj + 3] * val;
            }
        }
        acc *= inv;
        float ov = acc - THRESH;
        p = ov > 0.f ? ov * ov : 0.f;
    }
    DPP5(p, op_add, 0.0f);
    float tot = rdlane(p, 31) + rdlane(p, 63);
    if ((tid & 63) == 0) atomicAdd(&pen[b], tot);
    __syncthreads();                            // all 4 wave-atomics issued+drained
    if (tid == 0) {
        __threadfence();                        // release our adds
        int old = atomicAdd(&cnt[b], 1);        // device-scope ticket
        if (old == TCH - 1) {                   // last block for this batch
            __threadfence();                    // acquire others' adds
            float pv = atomicAdd(&pen[b], 0.0f);  // RMW -> latest value
            out[b] = W_WL * hpwl[b] + W_CONG * pv;
        }
    }
}

} // namespace

extern "C" void kernel_launch(void* const* d_in, const int* in_sizes, int n_in,
                              void* d_out, int out_size, void* d_ws, size_t ws_size,
                              hipStream_t stream) {
    const float* positions    = (const float*)d_in[0];
    const int*   net_to_pin   = (const int*)d_in[1];
    const int*   pin_to_macro = (const int*)d_in[2];
    const float* pin_offsets  = (const float*)d_in[3];
    const float* rot_onehot   = (const float*)d_in[4];
    const float* net_weights  = (const float*)d_in[5];
    float* out = (float*)d_out;

    // ws: pin_pos | hpwl | pen | cnt | fac | n2pT   (~25.6+6.4+12.8 MB)
    // slabs (512*16KB = 8.4 MB) ALIASES pin_pos (12.8 MB): pin_pos is dead
    // after bbox_kernel, and rudy_kernel runs strictly after it on the stream.
    float*  pin_pos = (float*)d_ws;
    float*  hpwl    = pin_pos + (size_t)B * P * 2;
    float*  pen     = hpwl + B;
    int*    cnt     = (int*)(pen + B);
    float4* fac     = (float4*)(cnt + B);              // B*NN*2 float4
    int*    n2pT    = (int*)(fac + (size_t)B * NN * 2);
    float*  slabs   = pin_pos;                 // reuse (see comment above)

    front_kernel<<<(PREP_N + 255) / 256, 256, 0, stream>>>(
        positions, rot_onehot, pin_to_macro, pin_offsets,
        net_to_pin, n2pT, pin_pos, hpwl, cnt);
    bbox_kernel<<<A_GRID, 256, 0, stream>>>(pin_pos, n2pT, net_weights, fac, hpwl);
    rudy_kernel<<<NET_GRID, 256, 0, stream>>>(fac, slabs);
    tail_kernel<<<TCH * B, 256, 0, stream>>>(slabs, hpwl, pen, cnt, out);
}